// Round 17
// baseline (288.687 us; speedup 1.0000x reference)
//
#include <hip/hip_runtime.h>
#include <cstddef>

#define B_     4096
#define L_     64
#define OUT_   64
#define KS_    8
#define KK_    4
#define LOUT_  57
#define C_     3648      // OUT_*LOUT_ = 57*64
#define HID_   33
#define TEMP_  34.0f
#define EPS_   1e-5f
#define NCH_   128       // b-chunks for stats (32 rows each)
#define SROWS_ 32        // rows per stats block
#define NB2_   32        // rows per block in write kernel
#define PLANE_ (SROWS_ * 17 + 2)   // padded s-plane stride (float4s)

typedef float f32x2 __attribute__((ext_vector_type(2)));

__device__ __forceinline__ f32x2 pk_fma(f32x2 a, f32x2 b, f32x2 c) {
    return __builtin_elementwise_fma(a, b, c);
}

// gelu tanh-form: x * sigmoid(1.5957691*x*(1+0.044715x^2)); max abs err ~5e-4.
__device__ __forceinline__ float gelu_f(float x) {
    float e = exp2f(-2.3022083f * x * fmaf(0.044715f * x, x, 1.0f));
    return x * __builtin_amdgcn_rcpf(1.0f + e);
}

// pairwise gelu: 5 packed VALU + 4 trans for two gelus.
__device__ __forceinline__ f32x2 gelu2(f32x2 x) {
    const f32x2 one = {1.f, 1.f};
    const f32x2 ca  = {0.044715f, 0.044715f};
    const f32x2 cb  = {-2.3022083f, -2.3022083f};
    f32x2 t = pk_fma(x * ca, x, one);        // 1 + a x^2
    f32x2 u = x * t * cb;
    f32x2 e = {exp2f(u.x), exp2f(u.y)};
    f32x2 d = e + one;
    f32x2 r = {__builtin_amdgcn_rcpf(d.x), __builtin_amdgcn_rcpf(d.y)};
    return x * r;
}

// Stage 32 rows of x into 4 byte-shifted LDS copies, s-plane padded (R14).
__device__ __forceinline__ void stage_shifted_p(
    const float* __restrict__ x, int b0, int tid, float4* xs4, int plane)
{
    for (int idx = tid; idx < SROWS_ * 16; idx += 256) {
        int r = idx >> 4, t = idx & 15;
        const float4* xrow = (const float4*)(x + (size_t)(b0 + r) * L_);
        float4 a  = xrow[t];
        float4 bq = xrow[t < 15 ? t + 1 : 15];
        int base = r * 17 + t;
        xs4[base]             = a;
        xs4[plane + base]     = make_float4(a.y, a.z, a.w, bq.x);
        xs4[2 * plane + base] = make_float4(a.z, a.w, bq.x, bq.y);
        xs4[3 * plane + base] = make_float4(a.w, bq.x, bq.y, bq.z);
    }
}

// ---------------- kernel 1: attention weights (4 lanes per row) ----------------
__global__ __launch_bounds__(256) void attn_kernel(
    const float* __restrict__ x, const float* __restrict__ fc1_w,
    const float* __restrict__ fc2_w, const float* __restrict__ fc2_b,
    float* __restrict__ attn_out)
{
    int tid = threadIdx.x;
    int r = tid >> 2, j = tid & 3;      // 64 rows/block, 4 lanes/row
    int b = blockIdx.x * 64 + r;
    const float4* xr4 = (const float4*)(x + (size_t)b * L_);
    float lg0 = 0.f, lg1 = 0.f, lg2 = 0.f, lg3 = 0.f;
    for (int h = j; h < HID_; h += 4) {
        const float4* f4 = (const float4*)(fc1_w + (size_t)h * L_);
        float acc = 0.f;
        #pragma unroll
        for (int i = 0; i < 16; ++i) {
            float4 xv = xr4[i], wv = f4[i];
            acc = fmaf(xv.x, wv.x, acc); acc = fmaf(xv.y, wv.y, acc);
            acc = fmaf(xv.z, wv.z, acc); acc = fmaf(xv.w, wv.w, acc);
        }
        float a = gelu_f(acc);
        lg0 = fmaf(a, fc2_w[h],             lg0);
        lg1 = fmaf(a, fc2_w[HID_ + h],      lg1);
        lg2 = fmaf(a, fc2_w[2 * HID_ + h],  lg2);
        lg3 = fmaf(a, fc2_w[3 * HID_ + h],  lg3);
    }
    lg0 += __shfl_xor(lg0, 1, 4); lg0 += __shfl_xor(lg0, 2, 4);
    lg1 += __shfl_xor(lg1, 1, 4); lg1 += __shfl_xor(lg1, 2, 4);
    lg2 += __shfl_xor(lg2, 1, 4); lg2 += __shfl_xor(lg2, 2, 4);
    lg3 += __shfl_xor(lg3, 1, 4); lg3 += __shfl_xor(lg3, 2, 4);
    if (j == 0) {
        float z0 = (lg0 + fc2_b[0]) * (1.0f / TEMP_);
        float z1 = (lg1 + fc2_b[1]) * (1.0f / TEMP_);
        float z2 = (lg2 + fc2_b[2]) * (1.0f / TEMP_);
        float z3 = (lg3 + fc2_b[3]) * (1.0f / TEMP_);
        float mx = fmaxf(fmaxf(z0, z1), fmaxf(z2, z3));
        float e0 = __expf(z0 - mx), e1 = __expf(z1 - mx);
        float e2 = __expf(z2 - mx), e3 = __expf(z3 - mx);
        float inv = __builtin_amdgcn_rcpf(e0 + e1 + e2 + e3);
        ((float4*)attn_out)[b] = make_float4(e0*inv, e1*inv, e2*inv, e3*inv);
    }
}

// ---------------- kernel 2: batch statistics + fused last-block finalize ----------
__global__ __launch_bounds__(256) void stats_kernel(
    const float* __restrict__ x, const float* __restrict__ weight,
    const float* __restrict__ bias, const float* __restrict__ attn,
    float* __restrict__ P, float* __restrict__ F,
    const float* __restrict__ gamma, const float* __restrict__ beta,
    int* __restrict__ counters, int use_partial)
{
    int cb = blockIdx.x;
    int chunk = blockIdx.y;
    int tid = threadIdx.x;
    int c = cb * 256 + tid;
    bool act = c < C_;
    int o = act ? (c / LOUT_) : 0;
    int l = act ? (c - o * LOUT_) : 0;
    int q = l >> 2, s = l & 3;

    f32x2 wp[KK_][4];
    float bk[KK_];
    #pragma unroll
    for (int k = 0; k < KK_; ++k) {
        bk[k] = bias[k * OUT_ + o];
        const float* wk = weight + (size_t)(k * OUT_ + o) * KS_;
        #pragma unroll
        for (int j = 0; j < 4; ++j) wp[k][j] = f32x2{wk[2*j], wk[2*j+1]};
    }

    __shared__ float4 xs4[4 * PLANE_];
    __shared__ float at[SROWS_][KK_];

    int b0 = chunk * SROWS_;
    stage_shifted_p(x, b0, tid, xs4, PLANE_);
    if (tid < SROWS_ * KK_) ((float*)at)[tid] = attn[(size_t)b0 * KK_ + tid];
    __syncthreads();

    float s1 = 0.f, s2 = 0.f;
    f32x2 t1v = {0.f, 0.f}, t2v = {0.f, 0.f};
    if (act) {
        const float4* base = &xs4[s * PLANE_ + q];
        #pragma unroll 4
        for (int r = 0; r < SROWS_; ++r) {
            float4 A  = base[r * 17];
            float4 Bv = base[r * 17 + 1];
            f32x2 xp[4] = {{A.x, A.y}, {A.z, A.w}, {Bv.x, Bv.y}, {Bv.z, Bv.w}};
            float kv[KK_];
            #pragma unroll
            for (int k = 0; k < KK_; ++k) {
                f32x2 acc = {bk[k], 0.f};
                #pragma unroll
                for (int j = 0; j < 4; ++j) acc = pk_fma(xp[j], wp[k][j], acc);
                kv[k] = acc.x + acc.y;
            }
            float ov = at[r][0] * kv[0];
            ov = fmaf(at[r][1], kv[1], ov);
            ov = fmaf(at[r][2], kv[2], ov);
            ov = fmaf(at[r][3], kv[3], ov);
            float g = gelu_f(ov);
            s1 += g; s2 = fmaf(g, g, s2);
            f32x2 g01 = gelu2(f32x2{kv[0], kv[1]});
            f32x2 g23 = gelu2(f32x2{kv[2], kv[3]});
            t1v = t1v + g01 + g23;
            t2v = pk_fma(g01, g01, t2v);
            t2v = pk_fma(g23, g23, t2v);
        }
    }
    float t1 = t1v.x + t1v.y, t2 = t2v.x + t2v.y;

    if (use_partial) {
        if (act) {
            size_t base = (size_t)chunk * 4 * C_ + c;
            P[base]          = s1;
            P[base + C_]     = s2;
            P[base + 2 * C_] = t1;
            P[base + 3 * C_] = t2;
        }
        // ---- last-block finalize for this c-tile (device-scope fence + counter) ----
        __threadfence();
        __shared__ int lastv;
        if (tid == 0) lastv = atomicAdd(&counters[cb], 1);
        __syncthreads();
        if (lastv == NCH_ - 1) {
            __threadfence();    // acquire: all tiles' partials visible
            if (act) {
                float a0 = 0.f, a1 = 0.f, a2 = 0.f, a3 = 0.f;
                for (int ch = 0; ch < NCH_; ++ch) {
                    size_t base = (size_t)ch * 4 * C_ + c;
                    a0 += P[base];
                    a1 += P[base + C_];
                    a2 += P[base + 2 * C_];
                    a3 += P[base + 3 * C_];
                }
                float m  = a0 * (1.0f / B_);
                float v  = a1 * (1.0f / B_) - m * m;
                float rs = rsqrtf(v + EPS_);
                float m2 = a2 * (1.0f / (B_ * KK_));
                float v2 = a3 * (1.0f / (B_ * KK_)) - m2 * m2;
                float rs2 = rsqrtf(v2 + EPS_);
                float ga = gamma[c], be = beta[c];
                F[c]          = rs * ga;             // scaleA
                F[C_ + c]     = be - m * rs * ga;    // shiftA
                F[2 * C_ + c] = rs2 * ga;            // scaleK
                F[3 * C_ + c] = be - m2 * rs2 * ga;  // shiftK
            }
            if (tid == 0) counters[cb] = 0;          // self-clean for graph replays
        }
    } else {
        if (act) {
            atomicAdd(&P[c], s1);
            atomicAdd(&P[C_ + c], s2);
            atomicAdd(&P[2 * C_ + c], t1);
            atomicAdd(&P[3 * C_ + c], t2);
        }
    }
}

// ---------------- kernel 3 (fallback only): reduce partials -> scale/shift --------
__global__ __launch_bounds__(256) void finalize_kernel(
    const float* __restrict__ P, const float* __restrict__ gamma,
    const float* __restrict__ beta, float* __restrict__ F)
{
    __shared__ float red[4][64];
    int t = threadIdx.x;
    int cl = t & 63;
    int s = t >> 6;
    int c = blockIdx.x * 64 + cl;
    float a = P[(size_t)s * C_ + c];
    red[s][cl] = a;
    __syncthreads();
    if (t < 64) {
        float a0 = red[0][cl], a1 = red[1][cl], a2 = red[2][cl], a3 = red[3][cl];
        float m  = a0 * (1.0f / B_);
        float v  = a1 * (1.0f / B_) - m * m;
        float rs = rsqrtf(v + EPS_);
        float m2 = a2 * (1.0f / (B_ * KK_));
        float v2 = a3 * (1.0f / (B_ * KK_)) - m2 * m2;
        float rs2 = rsqrtf(v2 + EPS_);
        float ga = gamma[c], be = beta[c];
        F[c]          = rs * ga;
        F[C_ + c]     = be - m * rs * ga;
        F[2 * C_ + c] = rs2 * ga;
        F[3 * C_ + c] = be - m2 * rs2 * ga;
    }
}

// ---------------- kernel 4: recompute + normalize + write (R14 best-known) --------
__global__ __launch_bounds__(256) void write_kernel(
    const float* __restrict__ x, const float* __restrict__ weight,
    const float* __restrict__ bias, const float* __restrict__ attn,
    const float* __restrict__ F,
    float* __restrict__ out0, float* __restrict__ kwout)
{
    int cc = blockIdx.x;    // 0..14
    int bg = blockIdx.y;    // 0..B/NB2_-1
    int tid = threadIdx.x;
    int c = cc * 256 + tid;
    bool act = c < C_;
    int o = act ? (c / LOUT_) : 0;
    int l = act ? (c - o * LOUT_) : 0;
    int q = l >> 2, s = l & 3;

    f32x2 wp[KK_][4];
    float bk[KK_];
    #pragma unroll
    for (int k = 0; k < KK_; ++k) {
        bk[k] = bias[k * OUT_ + o];
        const float* wk = weight + (size_t)(k * OUT_ + o) * KS_;
        #pragma unroll
        for (int j = 0; j < 4; ++j) wp[k][j] = f32x2{wk[2*j], wk[2*j+1]};
    }
    float sA = 0.f, hA = 0.f, sK = 0.f, hK = 0.f;
    if (act) {
        sA = F[c]; hA = F[C_ + c]; sK = F[2 * C_ + c]; hK = F[3 * C_ + c];
    }
    f32x2 sk2 = {sK, sK}, hk2 = {hK, hK};

    __shared__ float4 xs4[4 * PLANE_];
    __shared__ float at[NB2_][KK_];
    int b0 = bg * NB2_;
    stage_shifted_p(x, b0, tid, xs4, PLANE_);
    if (tid < NB2_ * KK_) ((float*)at)[tid] = attn[(size_t)b0 * KK_ + tid];
    __syncthreads();

    if (!act) return;

    const float4* xbase = &xs4[s * PLANE_ + q];
    #pragma unroll 4
    for (int r = 0; r < NB2_; ++r) {
        float4 A  = xbase[r * 17];
        float4 Bv = xbase[r * 17 + 1];
        f32x2 xp[4] = {{A.x, A.y}, {A.z, A.w}, {Bv.x, Bv.y}, {Bv.z, Bv.w}};
        float kv[KK_];
        #pragma unroll
        for (int k = 0; k < KK_; ++k) {
            f32x2 acc = {bk[k], 0.f};
            #pragma unroll
            for (int j = 0; j < 4; ++j) acc = pk_fma(xp[j], wp[k][j], acc);
            kv[k] = acc.x + acc.y;
        }
        float ov = at[r][0] * kv[0];
        ov = fmaf(at[r][1], kv[1], ov);
        ov = fmaf(at[r][2], kv[2], ov);
        ov = fmaf(at[r][3], kv[3], ov);
        int b = b0 + r;
        float g = gelu_f(ov);
        out0[(size_t)b * C_ + c] = fmaf(g, sA, hA);
        f32x2 g01 = gelu2(f32x2{kv[0], kv[1]});
        f32x2 g23 = gelu2(f32x2{kv[2], kv[3]});
        f32x2 r01 = pk_fma(g01, sk2, hk2);
        f32x2 r23 = pk_fma(g23, sk2, hk2);
        float* base = kwout + (size_t)b * KK_ * C_ + c;
        base[0]      = r01.x;
        base[C_]     = r01.y;
        base[2 * C_] = r23.x;
        base[3 * C_] = r23.y;
    }
}

extern "C" void kernel_launch(void* const* d_in, const int* in_sizes, int n_in,
                              void* d_out, int out_size, void* d_ws, size_t ws_size,
                              hipStream_t stream) {
    const float* x      = (const float*)d_in[0];
    const float* fc1_w  = (const float*)d_in[1];
    const float* fc2_w  = (const float*)d_in[2];
    const float* fc2_b  = (const float*)d_in[3];
    const float* weight = (const float*)d_in[4];
    const float* bias   = (const float*)d_in[5];
    const float* gamma  = (const float*)d_in[6];
    const float* beta   = (const float*)d_in[7];

    float* out  = (float*)d_out;
    float* out0 = out;                          // B*C
    float* attn = out + (size_t)B_ * C_;        // B*K
    float* kwout = attn + (size_t)B_ * KK_;     // B*K*C

    // ws layout: P (NCH_*4*C_) | F (4*C_) | counters (16 ints).
    size_t need = (size_t)(NCH_ * 4 + 4) * C_ * sizeof(float) + 16 * sizeof(int);
    int use_partial = ws_size >= need;
    float* P = (float*)d_ws;
    float* F = P + (use_partial ? (size_t)NCH_ * 4 * C_ : (size_t)4 * C_);
    int* counters = (int*)(F + 4 * C_);

    if (use_partial) {
        hipMemsetAsync(counters, 0, 16 * sizeof(int), stream);   // 64 B guard
        attn_kernel<<<B_ / 64, 256, 0, stream>>>(x, fc1_w, fc2_w, fc2_b, attn);
        stats_kernel<<<dim3(15, NCH_), 256, 0, stream>>>(
            x, weight, bias, attn, P, F, gamma, beta, counters, 1);
        write_kernel<<<dim3(15, B_ / NB2_), 256, 0, stream>>>(
            x, weight, bias, attn, F, out0, kwout);
    } else {
        hipMemsetAsync(P, 0, 4 * C_ * sizeof(float), stream);
        attn_kernel<<<B_ / 64, 256, 0, stream>>>(x, fc1_w, fc2_w, fc2_b, attn);
        stats_kernel<<<dim3(15, NCH_), 256, 0, stream>>>(
            x, weight, bias, attn, P, F, gamma, beta, counters, 0);
        finalize_kernel<<<C_ / 64, 256, 0, stream>>>(P, gamma, beta, F);
        write_kernel<<<dim3(15, B_ / NB2_), 256, 0, stream>>>(
            x, weight, bias, attn, F, out0, kwout);
    }
}

// Round 18
// 132.967 us; speedup vs baseline: 2.1711x; 2.1711x over previous
//
#include <hip/hip_runtime.h>
#include <cstddef>

#define B_     4096
#define L_     64
#define OUT_   64
#define KS_    8
#define KK_    4
#define LOUT_  57
#define C_     3648      // OUT_*LOUT_ = 57*64
#define HID_   33
#define TEMP_  34.0f
#define EPS_   1e-5f
#define NCH_   128       // b-chunks for stats (32 rows each)
#define SROWS_ 32        // rows per stats block
#define NB2_   32        // rows per block in write kernel
#define PLANE_ (SROWS_ * 17 + 2)   // padded s-plane stride (float4s)
#define RED1_  8         // finalize stage-A blocks per c-tile (each sums NCH_/RED1_ chunks)

typedef float f32x2 __attribute__((ext_vector_type(2)));

__device__ __forceinline__ f32x2 pk_fma(f32x2 a, f32x2 b, f32x2 c) {
    return __builtin_elementwise_fma(a, b, c);
}

// gelu tanh-form: x * sigmoid(1.5957691*x*(1+0.044715x^2)); max abs err ~5e-4.
__device__ __forceinline__ float gelu_f(float x) {
    float e = exp2f(-2.3022083f * x * fmaf(0.044715f * x, x, 1.0f));
    return x * __builtin_amdgcn_rcpf(1.0f + e);
}

// pairwise gelu: 5 packed VALU + 4 trans for two gelus.
__device__ __forceinline__ f32x2 gelu2(f32x2 x) {
    const f32x2 one = {1.f, 1.f};
    const f32x2 ca  = {0.044715f, 0.044715f};
    const f32x2 cb  = {-2.3022083f, -2.3022083f};
    f32x2 t = pk_fma(x * ca, x, one);        // 1 + a x^2
    f32x2 u = x * t * cb;
    f32x2 e = {exp2f(u.x), exp2f(u.y)};
    f32x2 d = e + one;
    f32x2 r = {__builtin_amdgcn_rcpf(d.x), __builtin_amdgcn_rcpf(d.y)};
    return x * r;
}

// Stage 32 rows of x into 4 byte-shifted LDS copies, s-plane padded (R14).
__device__ __forceinline__ void stage_shifted_p(
    const float* __restrict__ x, int b0, int tid, float4* xs4, int plane)
{
    for (int idx = tid; idx < SROWS_ * 16; idx += 256) {
        int r = idx >> 4, t = idx & 15;
        const float4* xrow = (const float4*)(x + (size_t)(b0 + r) * L_);
        float4 a  = xrow[t];
        float4 bq = xrow[t < 15 ? t + 1 : 15];
        int base = r * 17 + t;
        xs4[base]             = a;
        xs4[plane + base]     = make_float4(a.y, a.z, a.w, bq.x);
        xs4[2 * plane + base] = make_float4(a.z, a.w, bq.x, bq.y);
        xs4[3 * plane + base] = make_float4(a.w, bq.x, bq.y, bq.z);
    }
}

// ---------------- kernel 1: attention weights (16 lanes per row, 256 blocks) ------
__global__ __launch_bounds__(256) void attn_kernel(
    const float* __restrict__ x, const float* __restrict__ fc1_w,
    const float* __restrict__ fc2_w, const float* __restrict__ fc2_b,
    float* __restrict__ attn_out)
{
    int tid = threadIdx.x;
    int r = tid >> 4, j = tid & 15;     // 16 rows/block, 16 lanes/row
    int b = blockIdx.x * 16 + r;
    const float4* xr4 = (const float4*)(x + (size_t)b * L_);
    float lg0 = 0.f, lg1 = 0.f, lg2 = 0.f, lg3 = 0.f;
    for (int h = j; h < HID_; h += 16) {       // 2-3 iterations
        const float4* f4 = (const float4*)(fc1_w + (size_t)h * L_);
        float acc = 0.f;
        #pragma unroll
        for (int i = 0; i < 16; ++i) {
            float4 xv = xr4[i], wv = f4[i];
            acc = fmaf(xv.x, wv.x, acc); acc = fmaf(xv.y, wv.y, acc);
            acc = fmaf(xv.z, wv.z, acc); acc = fmaf(xv.w, wv.w, acc);
        }
        float a = gelu_f(acc);
        lg0 = fmaf(a, fc2_w[h],             lg0);
        lg1 = fmaf(a, fc2_w[HID_ + h],      lg1);
        lg2 = fmaf(a, fc2_w[2 * HID_ + h],  lg2);
        lg3 = fmaf(a, fc2_w[3 * HID_ + h],  lg3);
    }
    #pragma unroll
    for (int m = 1; m < 16; m <<= 1) {
        lg0 += __shfl_xor(lg0, m, 16);
        lg1 += __shfl_xor(lg1, m, 16);
        lg2 += __shfl_xor(lg2, m, 16);
        lg3 += __shfl_xor(lg3, m, 16);
    }
    if (j == 0) {
        float z0 = (lg0 + fc2_b[0]) * (1.0f / TEMP_);
        float z1 = (lg1 + fc2_b[1]) * (1.0f / TEMP_);
        float z2 = (lg2 + fc2_b[2]) * (1.0f / TEMP_);
        float z3 = (lg3 + fc2_b[3]) * (1.0f / TEMP_);
        float mx = fmaxf(fmaxf(z0, z1), fmaxf(z2, z3));
        float e0 = __expf(z0 - mx), e1 = __expf(z1 - mx);
        float e2 = __expf(z2 - mx), e3 = __expf(z3 - mx);
        float inv = __builtin_amdgcn_rcpf(e0 + e1 + e2 + e3);
        ((float4*)attn_out)[b] = make_float4(e0*inv, e1*inv, e2*inv, e3*inv);
    }
}

// ---------------- kernel 2: batch statistics (R14 best-known) ----------------
__global__ __launch_bounds__(256) void stats_kernel(
    const float* __restrict__ x, const float* __restrict__ weight,
    const float* __restrict__ bias, const float* __restrict__ attn,
    float* __restrict__ P, int use_partial)
{
    int cb = blockIdx.x;
    int chunk = blockIdx.y;
    int tid = threadIdx.x;
    int c = cb * 256 + tid;
    bool act = c < C_;
    int o = act ? (c / LOUT_) : 0;
    int l = act ? (c - o * LOUT_) : 0;
    int q = l >> 2, s = l & 3;

    f32x2 wp[KK_][4];
    float bk[KK_];
    #pragma unroll
    for (int k = 0; k < KK_; ++k) {
        bk[k] = bias[k * OUT_ + o];
        const float* wk = weight + (size_t)(k * OUT_ + o) * KS_;
        #pragma unroll
        for (int j = 0; j < 4; ++j) wp[k][j] = f32x2{wk[2*j], wk[2*j+1]};
    }

    __shared__ float4 xs4[4 * PLANE_];
    __shared__ float at[SROWS_][KK_];

    int b0 = chunk * SROWS_;
    stage_shifted_p(x, b0, tid, xs4, PLANE_);
    if (tid < SROWS_ * KK_) ((float*)at)[tid] = attn[(size_t)b0 * KK_ + tid];
    __syncthreads();

    float s1 = 0.f, s2 = 0.f;
    f32x2 t1v = {0.f, 0.f}, t2v = {0.f, 0.f};
    if (act) {
        const float4* base = &xs4[s * PLANE_ + q];
        #pragma unroll 4
        for (int r = 0; r < SROWS_; ++r) {
            float4 A  = base[r * 17];
            float4 Bv = base[r * 17 + 1];
            f32x2 xp[4] = {{A.x, A.y}, {A.z, A.w}, {Bv.x, Bv.y}, {Bv.z, Bv.w}};
            float kv[KK_];
            #pragma unroll
            for (int k = 0; k < KK_; ++k) {
                f32x2 acc = {bk[k], 0.f};
                #pragma unroll
                for (int j = 0; j < 4; ++j) acc = pk_fma(xp[j], wp[k][j], acc);
                kv[k] = acc.x + acc.y;
            }
            float ov = at[r][0] * kv[0];
            ov = fmaf(at[r][1], kv[1], ov);
            ov = fmaf(at[r][2], kv[2], ov);
            ov = fmaf(at[r][3], kv[3], ov);
            float g = gelu_f(ov);
            s1 += g; s2 = fmaf(g, g, s2);
            f32x2 g01 = gelu2(f32x2{kv[0], kv[1]});
            f32x2 g23 = gelu2(f32x2{kv[2], kv[3]});
            t1v = t1v + g01 + g23;
            t2v = pk_fma(g01, g01, t2v);
            t2v = pk_fma(g23, g23, t2v);
        }
    }
    if (!act) return;
    float t1 = t1v.x + t1v.y, t2 = t2v.x + t2v.y;
    if (use_partial) {
        size_t base = (size_t)chunk * 4 * C_ + c;
        P[base]          = s1;
        P[base + C_]     = s2;
        P[base + 2 * C_] = t1;
        P[base + 3 * C_] = t2;
    } else {
        atomicAdd(&P[c], s1);
        atomicAdd(&P[C_ + c], s2);
        atomicAdd(&P[2 * C_ + c], t1);
        atomicAdd(&P[3 * C_ + c], t2);
    }
}

// ---------------- kernel 3a: finalize stage A — tree-reduce chunks ----------------
// grid (15 c-tiles, RED1_); block g sums chunks [g*16, g*16+16) -> P2[g]
__global__ __launch_bounds__(256) void reduce_kernel(
    const float* __restrict__ P, float* __restrict__ P2)
{
    int cb = blockIdx.x, g = blockIdx.y;
    int tid = threadIdx.x;
    int c = cb * 256 + tid;
    if (c >= C_) return;
    const int CH = NCH_ / RED1_;    // 16
    float a0 = 0.f, a1 = 0.f, a2 = 0.f, a3 = 0.f;
    #pragma unroll 4
    for (int i = 0; i < CH; ++i) {
        size_t base = (size_t)(g * CH + i) * 4 * C_ + c;
        a0 += P[base];
        a1 += P[base + C_];
        a2 += P[base + 2 * C_];
        a3 += P[base + 3 * C_];
    }
    size_t ob = (size_t)g * 4 * C_ + c;
    P2[ob]          = a0;
    P2[ob + C_]     = a1;
    P2[ob + 2 * C_] = a2;
    P2[ob + 3 * C_] = a3;
}

// ---------------- kernel 3b: finalize stage B — fold into scale/shift -------------
__global__ __launch_bounds__(256) void finalize_kernel(
    const float* __restrict__ P2, const float* __restrict__ gamma,
    const float* __restrict__ beta, float* __restrict__ F, int nsrc)
{
    int c = blockIdx.x * 256 + threadIdx.x;
    if (c >= C_) return;
    float a0 = 0.f, a1 = 0.f, a2 = 0.f, a3 = 0.f;
    #pragma unroll 8
    for (int g = 0; g < nsrc; ++g) {
        size_t base = (size_t)g * 4 * C_ + c;
        a0 += P2[base];
        a1 += P2[base + C_];
        a2 += P2[base + 2 * C_];
        a3 += P2[base + 3 * C_];
    }
    float m  = a0 * (1.0f / B_);
    float v  = a1 * (1.0f / B_) - m * m;
    float rs = rsqrtf(v + EPS_);
    float m2 = a2 * (1.0f / (B_ * KK_));
    float v2 = a3 * (1.0f / (B_ * KK_)) - m2 * m2;
    float rs2 = rsqrtf(v2 + EPS_);
    float ga = gamma[c], be = beta[c];
    F[c]          = rs * ga;             // scaleA
    F[C_ + c]     = be - m * rs * ga;    // shiftA
    F[2 * C_ + c] = rs2 * ga;            // scaleK
    F[3 * C_ + c] = be - m2 * rs2 * ga;  // shiftK
}

// ---------------- kernel 4: recompute + normalize + write (R14 best-known) --------
__global__ __launch_bounds__(256) void write_kernel(
    const float* __restrict__ x, const float* __restrict__ weight,
    const float* __restrict__ bias, const float* __restrict__ attn,
    const float* __restrict__ F,
    float* __restrict__ out0, float* __restrict__ kwout)
{
    int cc = blockIdx.x;    // 0..14
    int bg = blockIdx.y;    // 0..B/NB2_-1
    int tid = threadIdx.x;
    int c = cc * 256 + tid;
    bool act = c < C_;
    int o = act ? (c / LOUT_) : 0;
    int l = act ? (c - o * LOUT_) : 0;
    int q = l >> 2, s = l & 3;

    f32x2 wp[KK_][4];
    float bk[KK_];
    #pragma unroll
    for (int k = 0; k < KK_; ++k) {
        bk[k] = bias[k * OUT_ + o];
        const float* wk = weight + (size_t)(k * OUT_ + o) * KS_;
        #pragma unroll
        for (int j = 0; j < 4; ++j) wp[k][j] = f32x2{wk[2*j], wk[2*j+1]};
    }
    float sA = 0.f, hA = 0.f, sK = 0.f, hK = 0.f;
    if (act) {
        sA = F[c]; hA = F[C_ + c]; sK = F[2 * C_ + c]; hK = F[3 * C_ + c];
    }
    f32x2 sk2 = {sK, sK}, hk2 = {hK, hK};

    __shared__ float4 xs4[4 * PLANE_];
    __shared__ float at[NB2_][KK_];
    int b0 = bg * NB2_;
    stage_shifted_p(x, b0, tid, xs4, PLANE_);
    if (tid < NB2_ * KK_) ((float*)at)[tid] = attn[(size_t)b0 * KK_ + tid];
    __syncthreads();

    if (!act) return;

    const float4* xbase = &xs4[s * PLANE_ + q];
    #pragma unroll 4
    for (int r = 0; r < NB2_; ++r) {
        float4 A  = xbase[r * 17];
        float4 Bv = xbase[r * 17 + 1];
        f32x2 xp[4] = {{A.x, A.y}, {A.z, A.w}, {Bv.x, Bv.y}, {Bv.z, Bv.w}};
        float kv[KK_];
        #pragma unroll
        for (int k = 0; k < KK_; ++k) {
            f32x2 acc = {bk[k], 0.f};
            #pragma unroll
            for (int j = 0; j < 4; ++j) acc = pk_fma(xp[j], wp[k][j], acc);
            kv[k] = acc.x + acc.y;
        }
        float ov = at[r][0] * kv[0];
        ov = fmaf(at[r][1], kv[1], ov);
        ov = fmaf(at[r][2], kv[2], ov);
        ov = fmaf(at[r][3], kv[3], ov);
        int b = b0 + r;
        float g = gelu_f(ov);
        out0[(size_t)b * C_ + c] = fmaf(g, sA, hA);
        f32x2 g01 = gelu2(f32x2{kv[0], kv[1]});
        f32x2 g23 = gelu2(f32x2{kv[2], kv[3]});
        f32x2 r01 = pk_fma(g01, sk2, hk2);
        f32x2 r23 = pk_fma(g23, sk2, hk2);
        float* base = kwout + (size_t)b * KK_ * C_ + c;
        base[0]      = r01.x;
        base[C_]     = r01.y;
        base[2 * C_] = r23.x;
        base[3 * C_] = r23.y;
    }
}

extern "C" void kernel_launch(void* const* d_in, const int* in_sizes, int n_in,
                              void* d_out, int out_size, void* d_ws, size_t ws_size,
                              hipStream_t stream) {
    const float* x      = (const float*)d_in[0];
    const float* fc1_w  = (const float*)d_in[1];
    const float* fc2_w  = (const float*)d_in[2];
    const float* fc2_b  = (const float*)d_in[3];
    const float* weight = (const float*)d_in[4];
    const float* bias   = (const float*)d_in[5];
    const float* gamma  = (const float*)d_in[6];
    const float* beta   = (const float*)d_in[7];

    float* out  = (float*)d_out;
    float* out0 = out;                          // B*C
    float* attn = out + (size_t)B_ * C_;        // B*K
    float* kwout = attn + (size_t)B_ * KK_;     // B*K*C

    // ws layout: P (NCH_*4*C_) | P2 (RED1_*4*C_) | F (4*C_).
    size_t need = (size_t)(NCH_ * 4 + RED1_ * 4 + 4) * C_ * sizeof(float);
    int use_partial = ws_size >= need;
    float* P  = (float*)d_ws;
    float* P2 = P + (use_partial ? (size_t)NCH_ * 4 * C_ : 0);
    float* F  = P2 + (use_partial ? (size_t)RED1_ * 4 * C_ : (size_t)4 * C_);

    attn_kernel<<<B_ / 16, 256, 0, stream>>>(x, fc1_w, fc2_w, fc2_b, attn);
    if (use_partial) {
        stats_kernel<<<dim3(15, NCH_), 256, 0, stream>>>(
            x, weight, bias, attn, P, 1);
        reduce_kernel<<<dim3(15, RED1_), 256, 0, stream>>>(P, P2);
        finalize_kernel<<<15, 256, 0, stream>>>(P2, gamma, beta, F, RED1_);
    } else {
        hipMemsetAsync(P, 0, 4 * C_ * sizeof(float), stream);
        stats_kernel<<<dim3(15, NCH_), 256, 0, stream>>>(
            x, weight, bias, attn, P, 0);
        finalize_kernel<<<15, 256, 0, stream>>>(P, gamma, beta, F, 1);
    }
    write_kernel<<<dim3(15, B_ / NB2_), 256, 0, stream>>>(
        x, weight, bias, attn, F, out0, kwout);
}